// Round 1
// baseline (296.725 us; speedup 1.0000x reference)
//
#include <hip/hip_runtime.h>

// Problem constants (B=1)
#define KK 12
#define LL 4096
#define DD 128
#define NN 16
#define RR 8
#define NC 64   // number of chunks
#define LC 64   // chunk length (NC*LC == LL)

// Decode sequence position l of direction k into spatial index (i1*16+i2)*16+i3.
// ORDERS = [(1,2,3),(1,3,2),(3,2,1),(3,1,2),(2,1,3),(2,3,1)]; odd k = flipped
// sequence = reversed order (digit complement of l).
__device__ __forceinline__ int pos_of(int k, int l) {
    int o = k >> 1;
    int le = (k & 1) ? (4095 - l) : l;
    int t1 = le >> 8, t2 = (le >> 4) & 15, t3 = le & 15;
    switch (o) {
        case 0:  return (t1 << 8) | (t2 << 4) | t3;
        case 1:  return (t1 << 8) | (t3 << 4) | t2;
        case 2:  return (t3 << 8) | (t2 << 4) | t1;
        case 3:  return (t2 << 8) | (t3 << 4) | t1;
        case 4:  return (t2 << 8) | (t1 << 4) | t3;
        default: return (t3 << 8) | (t1 << 4) | t2;
    }
}

__device__ __forceinline__ float softplus_f(float z) {
    return fmaxf(z, 0.0f) + log1pf(__expf(-fabsf(z)));
}

// ---------------------------------------------------------------------------
// Kernel 1: projection. One wave per (k, 64-l tile).
// Lane = l. Computes x_dbl[40] per l (W loads are wave-uniform -> scalar),
// stores B/C as [k][l][n], then transposes dts(r=0..7) through LDS and emits
// delta[k][l][d] coalesced (lanes = d).
// ---------------------------------------------------------------------------
__global__ __launch_bounds__(64) void proj_kernel(
    const float* __restrict__ x, const float* __restrict__ Wp,
    const float* __restrict__ Wdt, const float* __restrict__ bias,
    float* __restrict__ delta, float* __restrict__ Bc, float* __restrict__ Cc)
{
    int k = blockIdx.x >> 6;
    int l0 = (blockIdx.x & 63) * 64;
    int lane = threadIdx.x;
    int l = l0 + lane;
    int xbase = pos_of(k, l) * DD;

    float acc[40];
    #pragma unroll
    for (int c = 0; c < 40; c++) acc[c] = 0.0f;

    const float* wk = Wp + k * 40 * DD;
    for (int d = 0; d < DD; d += 4) {
        float4 xv = *(const float4*)(x + xbase + d);
        #pragma unroll
        for (int c = 0; c < 40; c++) {
            const float* w = wk + c * DD + d;   // wave-uniform -> s_load
            acc[c] += xv.x * w[0] + xv.y * w[1] + xv.z * w[2] + xv.w * w[3];
        }
    }

    float4* bdst = (float4*)(Bc + (size_t)(k * LL + l) * NN);
    bdst[0] = make_float4(acc[8],  acc[9],  acc[10], acc[11]);
    bdst[1] = make_float4(acc[12], acc[13], acc[14], acc[15]);
    bdst[2] = make_float4(acc[16], acc[17], acc[18], acc[19]);
    bdst[3] = make_float4(acc[20], acc[21], acc[22], acc[23]);
    float4* cdst = (float4*)(Cc + (size_t)(k * LL + l) * NN);
    cdst[0] = make_float4(acc[24], acc[25], acc[26], acc[27]);
    cdst[1] = make_float4(acc[28], acc[29], acc[30], acc[31]);
    cdst[2] = make_float4(acc[32], acc[33], acc[34], acc[35]);
    cdst[3] = make_float4(acc[36], acc[37], acc[38], acc[39]);

    __shared__ float sdts[64][9];   // +1 pad
    #pragma unroll
    for (int r = 0; r < 8; r++) sdts[lane][r] = acc[r];
    __syncthreads();

    // delta phase: lanes over d (lane and lane+64)
    int da = lane, db = lane + 64;
    const float4* wpa = (const float4*)(Wdt + k * DD * RR + da * RR);
    const float4* wpb = (const float4*)(Wdt + k * DD * RR + db * RR);
    float4 wa0 = wpa[0], wa1 = wpa[1], wb0 = wpb[0], wb1 = wpb[1];
    float ba = bias[k * DD + da], bb = bias[k * DD + db];

    for (int j = 0; j < 64; j++) {
        float z0 = ba, z1 = bb;
        float t0 = sdts[j][0], t1 = sdts[j][1], t2 = sdts[j][2], t3 = sdts[j][3];
        float t4 = sdts[j][4], t5 = sdts[j][5], t6 = sdts[j][6], t7 = sdts[j][7];
        z0 += wa0.x*t0 + wa0.y*t1 + wa0.z*t2 + wa0.w*t3
            + wa1.x*t4 + wa1.y*t5 + wa1.z*t6 + wa1.w*t7;
        z1 += wb0.x*t0 + wb0.y*t1 + wb0.z*t2 + wb0.w*t3
            + wb1.x*t4 + wb1.y*t5 + wb1.z*t6 + wb1.w*t7;
        delta[(size_t)(k * LL + l0 + j) * DD + da] = softplus_f(z0);
        delta[(size_t)(k * LL + l0 + j) * DD + db] = softplus_f(z1);
    }
}

// ---------------------------------------------------------------------------
// Kernel 2: scan phase A — per-chunk local scan with h0 = 0.
// Block = (k, chunk), thread = d. Stores local end-state S[16] and sum(dt).
// ---------------------------------------------------------------------------
__global__ __launch_bounds__(128) void scanA_kernel(
    const float* __restrict__ x, const float* __restrict__ delta,
    const float* __restrict__ Bc, const float* __restrict__ A_logs,
    float* __restrict__ Sb, float* __restrict__ dtsum)
{
    int k = blockIdx.x >> 6;
    int c = blockIdx.x & 63;
    int d = threadIdx.x;
    int l0 = c * LC;

    float Av[16];
    const float4* ap = (const float4*)(A_logs + (size_t)(k * DD + d) * NN);
    #pragma unroll
    for (int q = 0; q < 4; q++) {
        float4 a4 = ap[q];
        Av[4*q+0] = -__expf(a4.x); Av[4*q+1] = -__expf(a4.y);
        Av[4*q+2] = -__expf(a4.z); Av[4*q+3] = -__expf(a4.w);
    }

    float h[16];
    #pragma unroll
    for (int n = 0; n < 16; n++) h[n] = 0.0f;
    float dsum = 0.0f;

    for (int i = 0; i < LC; i++) {
        int l = l0 + i;
        float t = delta[(size_t)(k * LL + l) * DD + d];       // coalesced
        float u = x[pos_of(k, l) * DD + d];                   // coalesced
        const float4* bp = (const float4*)(Bc + (size_t)(k * LL + l) * NN); // broadcast
        float Bv[16];
        #pragma unroll
        for (int q = 0; q < 4; q++) {
            float4 b4 = bp[q];
            Bv[4*q] = b4.x; Bv[4*q+1] = b4.y; Bv[4*q+2] = b4.z; Bv[4*q+3] = b4.w;
        }
        dsum += t;
        float tu = t * u;
        #pragma unroll
        for (int n = 0; n < 16; n++)
            h[n] = __expf(t * Av[n]) * h[n] + tu * Bv[n];
    }

    float4* sp = (float4*)(Sb + (size_t)((k * NC + c) * DD + d) * NN);
    sp[0] = make_float4(h[0],  h[1],  h[2],  h[3]);
    sp[1] = make_float4(h[4],  h[5],  h[6],  h[7]);
    sp[2] = make_float4(h[8],  h[9],  h[10], h[11]);
    sp[3] = make_float4(h[12], h[13], h[14], h[15]);
    dtsum[(k * NC + c) * DD + d] = dsum;
}

// ---------------------------------------------------------------------------
// Kernel 3: scan phase B — sequential combine across chunks.
// Thread = (k,d,n). Chunk product of dA = exp(A * sum_dt). Emits each chunk's
// true initial state hs.
// ---------------------------------------------------------------------------
__global__ __launch_bounds__(256) void scanB_kernel(
    const float* __restrict__ Sb, const float* __restrict__ dtsum,
    const float* __restrict__ A_logs, float* __restrict__ hs)
{
    int tid = blockIdx.x * 256 + threadIdx.x;   // k*2048 + d*16 + n
    int k = tid >> 11;
    int rem = tid & 2047;
    int d = rem >> 4;

    float Av = -__expf(A_logs[tid]);
    float h = 0.0f;
    #pragma unroll 8
    for (int c = 0; c < NC; c++) {
        int base = k * (NC * DD * NN) + c * (DD * NN) + rem;
        hs[base] = h;
        float s = Sb[base];
        float ds = dtsum[(k * NC + c) * DD + d];
        h = s + __expf(ds * Av) * h;
    }
}

// ---------------------------------------------------------------------------
// Kernel 4: scan phase C — per-chunk scan from true initial state, emits y.
// out_y layout [k][d][l]; 16-l register buffer -> full-line 64B stores.
// ---------------------------------------------------------------------------
__global__ __launch_bounds__(128) void scanC_kernel(
    const float* __restrict__ x, const float* __restrict__ delta,
    const float* __restrict__ Bc, const float* __restrict__ Cc,
    const float* __restrict__ A_logs, const float* __restrict__ Ds,
    const float* __restrict__ hs, float* __restrict__ out_y)
{
    int k = blockIdx.x >> 6;
    int c = blockIdx.x & 63;
    int d = threadIdx.x;
    int l0 = c * LC;

    float Av[16];
    const float4* ap = (const float4*)(A_logs + (size_t)(k * DD + d) * NN);
    #pragma unroll
    for (int q = 0; q < 4; q++) {
        float4 a4 = ap[q];
        Av[4*q+0] = -__expf(a4.x); Av[4*q+1] = -__expf(a4.y);
        Av[4*q+2] = -__expf(a4.z); Av[4*q+3] = -__expf(a4.w);
    }

    float h[16];
    const float4* hp = (const float4*)(hs + (size_t)((k * NC + c) * DD + d) * NN);
    #pragma unroll
    for (int q = 0; q < 4; q++) {
        float4 h4 = hp[q];
        h[4*q] = h4.x; h[4*q+1] = h4.y; h[4*q+2] = h4.z; h[4*q+3] = h4.w;
    }

    float Dval = Ds[k * DD + d];
    float obuf[16];

    for (int i = 0; i < LC; i++) {
        int l = l0 + i;
        float t = delta[(size_t)(k * LL + l) * DD + d];
        float u = x[pos_of(k, l) * DD + d];
        const float4* bp = (const float4*)(Bc + (size_t)(k * LL + l) * NN);
        const float4* cp = (const float4*)(Cc + (size_t)(k * LL + l) * NN);
        float Bv[16], Cv[16];
        #pragma unroll
        for (int q = 0; q < 4; q++) {
            float4 b4 = bp[q]; float4 c4 = cp[q];
            Bv[4*q] = b4.x; Bv[4*q+1] = b4.y; Bv[4*q+2] = b4.z; Bv[4*q+3] = b4.w;
            Cv[4*q] = c4.x; Cv[4*q+1] = c4.y; Cv[4*q+2] = c4.z; Cv[4*q+3] = c4.w;
        }
        float tu = t * u;
        float y = 0.0f;
        #pragma unroll
        for (int n = 0; n < 16; n++) {
            h[n] = __expf(t * Av[n]) * h[n] + tu * Bv[n];
            y += h[n] * Cv[n];
        }
        obuf[i & 15] = y + Dval * u;
        if ((i & 15) == 15) {
            float4* op = (float4*)(out_y + (size_t)(k * DD + d) * LL + (l0 + (i & ~15)));
            op[0] = make_float4(obuf[0],  obuf[1],  obuf[2],  obuf[3]);
            op[1] = make_float4(obuf[4],  obuf[5],  obuf[6],  obuf[7]);
            op[2] = make_float4(obuf[8],  obuf[9],  obuf[10], obuf[11]);
            op[3] = make_float4(obuf[12], obuf[13], obuf[14], obuf[15]);
        }
    }
}

// ---------------------------------------------------------------------------
// Kernel 5: restore + merge. Replicates the reference's (D,L)-flat reshape:
// f = ((j1*16+j2)*16+j3)*128 + dd ; d = f>>12 ; l = f&4095.
// With out_y [k][d][l], lanes (consecutive dd) read consecutive l -> coalesced.
// ---------------------------------------------------------------------------
__global__ __launch_bounds__(256) void merge_kernel(
    const float* __restrict__ out_y, const float* __restrict__ mw,
    const float* __restrict__ mb, float* __restrict__ out)
{
    int idx = blockIdx.x * 256 + threadIdx.x;
    int dd = idx & 127;
    int p = idx >> 7;
    int i3 = p & 15, i2 = (p >> 4) & 15, i1 = (p >> 8) & 15;

    float accv = mb[0];
    #pragma unroll
    for (int k = 0; k < 12; k++) {
        int a1 = i1, a2 = i2, a3 = i3;
        if (k & 1) { a1 = 15 - i1; a2 = 15 - i2; a3 = 15 - i3; }
        int j1, j2, j3;
        switch (k >> 1) {
            case 0:  j1 = a1; j2 = a2; j3 = a3; break;
            case 1:  j1 = a1; j2 = a3; j3 = a2; break;
            case 2:  j1 = a3; j2 = a2; j3 = a1; break;
            case 3:  j1 = a3; j2 = a1; j3 = a2; break;
            case 4:  j1 = a2; j2 = a1; j3 = a3; break;
            default: j1 = a2; j2 = a3; j3 = a1; break;
        }
        int jb = (j1 << 8) | (j2 << 4) | j3;
        accv += mw[k] * out_y[(size_t)k * (DD * LL) + (jb >> 5) * LL + ((jb & 31) << 7) + dd];
    }
    out[idx] = accv;
}

extern "C" void kernel_launch(void* const* d_in, const int* in_sizes, int n_in,
                              void* d_out, int out_size, void* d_ws, size_t ws_size,
                              hipStream_t stream) {
    const float* x      = (const float*)d_in[0];   // (1,16,16,16,128)
    const float* Wp     = (const float*)d_in[1];   // (12,40,128)
    const float* Wdt    = (const float*)d_in[2];   // (12,128,8)
    const float* bias   = (const float*)d_in[3];   // (12,128)
    const float* A_logs = (const float*)d_in[4];   // (12,128,16)
    const float* Ds     = (const float*)d_in[5];   // (12,128)
    const float* mw     = (const float*)d_in[6];   // (12,)
    const float* mb     = (const float*)d_in[7];   // scalar
    float* out = (float*)d_out;

    float* ws    = (float*)d_ws;
    float* delta = ws;                              // K*L*D   = 6291456
    float* Bc    = delta + (size_t)KK * LL * DD;    // K*L*N   =  786432
    float* Cc    = Bc    + (size_t)KK * LL * NN;    // K*L*N   =  786432
    float* Sb    = Cc    + (size_t)KK * LL * NN;    // K*NC*D*N = 1572864
    float* dts   = Sb    + (size_t)KK * NC * DD * NN; // K*NC*D =  98304
    float* hs    = dts   + (size_t)KK * NC * DD;    // K*NC*D*N = 1572864
    float* oy    = hs    + (size_t)KK * NC * DD * NN; // K*D*L = 6291456

    proj_kernel <<<dim3(KK * (LL / 64)), dim3(64),  0, stream>>>(x, Wp, Wdt, bias, delta, Bc, Cc);
    scanA_kernel<<<dim3(KK * NC),        dim3(128), 0, stream>>>(x, delta, Bc, A_logs, Sb, dts);
    scanB_kernel<<<dim3(KK * DD * NN / 256), dim3(256), 0, stream>>>(Sb, dts, A_logs, hs);
    scanC_kernel<<<dim3(KK * NC),        dim3(128), 0, stream>>>(x, delta, Bc, Cc, A_logs, Ds, hs, oy);
    merge_kernel<<<dim3(LL * DD / 256),  dim3(256), 0, stream>>>(oy, mw, mb, out);
}

// Round 2
// 187.390 us; speedup vs baseline: 1.5835x; 1.5835x over previous
//
#include <hip/hip_runtime.h>

// Problem constants (B=1)
#define KK 12
#define LL 4096
#define DD 128
#define NN 16
#define RR 8
#define NC 128  // number of chunks
#define LC 32   // chunk length (NC*LC == LL)

// Decode sequence position l of direction k into spatial index (i1*16+i2)*16+i3.
__device__ __forceinline__ int pos_of(int k, int l) {
    int o = k >> 1;
    int le = (k & 1) ? (4095 - l) : l;
    int t1 = le >> 8, t2 = (le >> 4) & 15, t3 = le & 15;
    switch (o) {
        case 0:  return (t1 << 8) | (t2 << 4) | t3;
        case 1:  return (t1 << 8) | (t3 << 4) | t2;
        case 2:  return (t3 << 8) | (t2 << 4) | t1;
        case 3:  return (t2 << 8) | (t3 << 4) | t1;
        case 4:  return (t2 << 8) | (t1 << 4) | t3;
        default: return (t3 << 8) | (t1 << 4) | t2;
    }
}

__device__ __forceinline__ float softplus_f(float z) {
    return fmaxf(z, 0.0f) + __logf(1.0f + __expf(-fabsf(z)));
}

// ---------------------------------------------------------------------------
// Kernel 1: projection + delta. Block = 256 threads, one (k, 64-l tile).
// Stage x tile (64 x 128, pad 132) into LDS coalesced; 4 waves each compute
// 10 of the 40 output channels (weights wave-uniform -> s_load); x_dbl goes
// back through LDS for the B/C stores and the delta (r=8 dot) phase.
// ---------------------------------------------------------------------------
__global__ __launch_bounds__(256) void proj_kernel(
    const float* __restrict__ x, const float* __restrict__ Wp,
    const float* __restrict__ Wdt, const float* __restrict__ bias,
    float* __restrict__ delta, float* __restrict__ Bc, float* __restrict__ Cc)
{
    int k = blockIdx.x >> 6;
    int l0 = (blockIdx.x & 63) * 64;
    int t = threadIdx.x;

    __shared__ float xs_s[64 * 132];

    // --- stage x tile: 8 passes, 8 rows/pass, 32 lanes * float4 per row ---
    {
        int lane32 = t & 31;
        int rowi = t >> 5;
        #pragma unroll
        for (int p = 0; p < 8; p++) {
            int l = p * 8 + rowi;
            int xbase = pos_of(k, l0 + l) * DD;
            float4 v = *(const float4*)(x + xbase + lane32 * 4);
            *(float4*)(&xs_s[l * 132 + lane32 * 4]) = v;
        }
    }
    __syncthreads();

    // --- compute: wave cg handles channels cg*10 .. cg*10+9 ---
    int l = t & 63;
    int cg = t >> 6;
    float acc[10];
    #pragma unroll
    for (int j = 0; j < 10; j++) acc[j] = 0.0f;
    {
        const float* wk = Wp + (size_t)(k * 40 + cg * 10) * DD;
        for (int d = 0; d < DD; d += 4) {
            float4 xv = *(const float4*)(&xs_s[l * 132 + d]);
            #pragma unroll
            for (int j = 0; j < 10; j++) {
                const float* w = wk + j * DD + d;   // wave-uniform
                acc[j] += xv.x * w[0] + xv.y * w[1] + xv.z * w[2] + xv.w * w[3];
            }
        }
    }
    __syncthreads();   // done reading x tile; reuse LDS

    // --- x_dbl to LDS: sdbl[c][l] ---
    float* sdbl = xs_s;   // 40*64 floats
    #pragma unroll
    for (int j = 0; j < 10; j++) sdbl[(cg * 10 + j) * 64 + l] = acc[j];
    __syncthreads();

    // --- B/C stores: t&3 = n-quad, t>>2 = l  (coalesced 64B per 4 lanes) ---
    {
        int n4 = t & 3;
        int ll = t >> 2;
        float4 bv = make_float4(sdbl[(8  + n4 * 4 + 0) * 64 + ll],
                                sdbl[(8  + n4 * 4 + 1) * 64 + ll],
                                sdbl[(8  + n4 * 4 + 2) * 64 + ll],
                                sdbl[(8  + n4 * 4 + 3) * 64 + ll]);
        *(float4*)(Bc + (size_t)(k * LL + l0 + ll) * NN + n4 * 4) = bv;
        float4 cv = make_float4(sdbl[(24 + n4 * 4 + 0) * 64 + ll],
                                sdbl[(24 + n4 * 4 + 1) * 64 + ll],
                                sdbl[(24 + n4 * 4 + 2) * 64 + ll],
                                sdbl[(24 + n4 * 4 + 3) * 64 + ll]);
        *(float4*)(Cc + (size_t)(k * LL + l0 + ll) * NN + n4 * 4) = cv;
    }

    // --- delta: thread = (d, half); 32 l's each; sdbl reads broadcast ---
    {
        int d = t & 127;
        int half = t >> 7;
        const float4* wp4 = (const float4*)(Wdt + (size_t)(k * DD + d) * RR);
        float4 w0 = wp4[0], w1 = wp4[1];
        float bz = bias[k * DD + d];
        for (int j = 0; j < 32; j++) {
            int ll = j * 2 + half;
            float z = bz
                + w0.x * sdbl[0 * 64 + ll] + w0.y * sdbl[1 * 64 + ll]
                + w0.z * sdbl[2 * 64 + ll] + w0.w * sdbl[3 * 64 + ll]
                + w1.x * sdbl[4 * 64 + ll] + w1.y * sdbl[5 * 64 + ll]
                + w1.z * sdbl[6 * 64 + ll] + w1.w * sdbl[7 * 64 + ll];
            delta[(size_t)(k * LL + l0 + ll) * DD + d] = softplus_f(z);
        }
    }
}

// Load -exp(A_logs) row and check the (n+1)*A0 structure for the power
// fast path (exp(t*A[n]) == q^(n+1), q = exp(t*A[0])).
__device__ __forceinline__ bool load_A(const float* __restrict__ A_logs,
                                       int k, int d, float* Av) {
    const float4* ap = (const float4*)(A_logs + (size_t)(k * DD + d) * NN);
    #pragma unroll
    for (int q = 0; q < 4; q++) {
        float4 a4 = ap[q];
        Av[4*q+0] = -__expf(a4.x); Av[4*q+1] = -__expf(a4.y);
        Av[4*q+2] = -__expf(a4.z); Av[4*q+3] = -__expf(a4.w);
    }
    bool s = true;
    #pragma unroll
    for (int n = 1; n < 16; n++)
        s = s && (fabsf(Av[n] - (float)(n + 1) * Av[0])
                  <= 1e-4f * (float)(n + 1) * fabsf(Av[0]));
    return s;
}

__device__ __forceinline__ void exp_vec(bool structured, float t,
                                        const float* Av, float* e) {
    if (structured) {
        float q = __expf(t * Av[0]);
        e[0] = q;
        #pragma unroll
        for (int n = 1; n < 16; n++) e[n] = e[n - 1] * q;
    } else {
        #pragma unroll
        for (int n = 0; n < 16; n++) e[n] = __expf(t * Av[n]);
    }
}

// ---------------------------------------------------------------------------
// Kernel 2: scan phase A — per-chunk local scan with h0 = 0.
// ---------------------------------------------------------------------------
__global__ __launch_bounds__(128) void scanA_kernel(
    const float* __restrict__ x, const float* __restrict__ delta,
    const float* __restrict__ Bc, const float* __restrict__ A_logs,
    float* __restrict__ Sb, float* __restrict__ dtsum)
{
    int k = blockIdx.x >> 7;
    int c = blockIdx.x & (NC - 1);
    int d = threadIdx.x;
    int l0 = c * LC;

    float Av[16];
    bool structured = load_A(A_logs, k, d, Av);

    float h[16];
    #pragma unroll
    for (int n = 0; n < 16; n++) h[n] = 0.0f;
    float dsum = 0.0f;

    for (int i = 0; i < LC; i++) {
        int l = l0 + i;
        float t = delta[(size_t)(k * LL + l) * DD + d];
        float u = x[pos_of(k, l) * DD + d];
        const float4* bp = (const float4*)(Bc + (size_t)(k * LL + l) * NN);
        float Bv[16];
        #pragma unroll
        for (int q = 0; q < 4; q++) {
            float4 b4 = bp[q];
            Bv[4*q] = b4.x; Bv[4*q+1] = b4.y; Bv[4*q+2] = b4.z; Bv[4*q+3] = b4.w;
        }
        dsum += t;
        float tu = t * u;
        float e[16];
        exp_vec(structured, t, Av, e);
        #pragma unroll
        for (int n = 0; n < 16; n++)
            h[n] = e[n] * h[n] + tu * Bv[n];
    }

    float4* sp = (float4*)(Sb + (size_t)((k * NC + c) * DD + d) * NN);
    sp[0] = make_float4(h[0],  h[1],  h[2],  h[3]);
    sp[1] = make_float4(h[4],  h[5],  h[6],  h[7]);
    sp[2] = make_float4(h[8],  h[9],  h[10], h[11]);
    sp[3] = make_float4(h[12], h[13], h[14], h[15]);
    dtsum[(k * NC + c) * DD + d] = dsum;
}

// ---------------------------------------------------------------------------
// Kernel 3: scan phase B — sequential combine across chunks, IN PLACE:
// Sb[c] is replaced by the true initial state of chunk c.
// ---------------------------------------------------------------------------
__global__ __launch_bounds__(256) void scanB_kernel(
    float* __restrict__ Sb, const float* __restrict__ dtsum,
    const float* __restrict__ A_logs)
{
    int tid = blockIdx.x * 256 + threadIdx.x;   // k*2048 + d*16 + n
    int k = tid >> 11;
    int rem = tid & 2047;
    int d = rem >> 4;

    float Av = -__expf(A_logs[tid]);
    float h = 0.0f;
    for (int c = 0; c < NC; c++) {
        size_t base = (size_t)k * (NC * DD * NN) + (size_t)c * (DD * NN) + rem;
        float s = Sb[base];
        float ds = dtsum[(k * NC + c) * DD + d];
        Sb[base] = h;
        h = s + __expf(ds * Av) * h;
    }
}

// ---------------------------------------------------------------------------
// Kernel 4: scan phase C — per-chunk scan from true initial state (in Sb),
// emits y. out_y layout [k][d][l]; 16-l register buffer -> 64B stores.
// ---------------------------------------------------------------------------
__global__ __launch_bounds__(128) void scanC_kernel(
    const float* __restrict__ x, const float* __restrict__ delta,
    const float* __restrict__ Bc, const float* __restrict__ Cc,
    const float* __restrict__ A_logs, const float* __restrict__ Ds,
    const float* __restrict__ hs, float* __restrict__ out_y)
{
    int k = blockIdx.x >> 7;
    int c = blockIdx.x & (NC - 1);
    int d = threadIdx.x;
    int l0 = c * LC;

    float Av[16];
    bool structured = load_A(A_logs, k, d, Av);

    float h[16];
    const float4* hp = (const float4*)(hs + (size_t)((k * NC + c) * DD + d) * NN);
    #pragma unroll
    for (int q = 0; q < 4; q++) {
        float4 h4 = hp[q];
        h[4*q] = h4.x; h[4*q+1] = h4.y; h[4*q+2] = h4.z; h[4*q+3] = h4.w;
    }

    float Dval = Ds[k * DD + d];
    float obuf[16];

    for (int i = 0; i < LC; i++) {
        int l = l0 + i;
        float t = delta[(size_t)(k * LL + l) * DD + d];
        float u = x[pos_of(k, l) * DD + d];
        const float4* bp = (const float4*)(Bc + (size_t)(k * LL + l) * NN);
        const float4* cp = (const float4*)(Cc + (size_t)(k * LL + l) * NN);
        float Bv[16], Cv[16];
        #pragma unroll
        for (int q = 0; q < 4; q++) {
            float4 b4 = bp[q]; float4 c4 = cp[q];
            Bv[4*q] = b4.x; Bv[4*q+1] = b4.y; Bv[4*q+2] = b4.z; Bv[4*q+3] = b4.w;
            Cv[4*q] = c4.x; Cv[4*q+1] = c4.y; Cv[4*q+2] = c4.z; Cv[4*q+3] = c4.w;
        }
        float tu = t * u;
        float e[16];
        exp_vec(structured, t, Av, e);
        float y = 0.0f;
        #pragma unroll
        for (int n = 0; n < 16; n++) {
            h[n] = e[n] * h[n] + tu * Bv[n];
            y += h[n] * Cv[n];
        }
        obuf[i & 15] = y + Dval * u;
        if ((i & 15) == 15) {
            float4* op = (float4*)(out_y + (size_t)(k * DD + d) * LL + (l0 + (i & ~15)));
            op[0] = make_float4(obuf[0],  obuf[1],  obuf[2],  obuf[3]);
            op[1] = make_float4(obuf[4],  obuf[5],  obuf[6],  obuf[7]);
            op[2] = make_float4(obuf[8],  obuf[9],  obuf[10], obuf[11]);
            op[3] = make_float4(obuf[12], obuf[13], obuf[14], obuf[15]);
        }
    }
}

// ---------------------------------------------------------------------------
// Kernel 5: restore + merge (replicates reference's (D,L)-flat reshape).
// ---------------------------------------------------------------------------
__global__ __launch_bounds__(256) void merge_kernel(
    const float* __restrict__ out_y, const float* __restrict__ mw,
    const float* __restrict__ mb, float* __restrict__ out)
{
    int idx = blockIdx.x * 256 + threadIdx.x;
    int dd = idx & 127;
    int p = idx >> 7;
    int i3 = p & 15, i2 = (p >> 4) & 15, i1 = (p >> 8) & 15;

    float accv = mb[0];
    #pragma unroll
    for (int k = 0; k < 12; k++) {
        int a1 = i1, a2 = i2, a3 = i3;
        if (k & 1) { a1 = 15 - i1; a2 = 15 - i2; a3 = 15 - i3; }
        int j1, j2, j3;
        switch (k >> 1) {
            case 0:  j1 = a1; j2 = a2; j3 = a3; break;
            case 1:  j1 = a1; j2 = a3; j3 = a2; break;
            case 2:  j1 = a3; j2 = a2; j3 = a1; break;
            case 3:  j1 = a3; j2 = a1; j3 = a2; break;
            case 4:  j1 = a2; j2 = a1; j3 = a3; break;
            default: j1 = a2; j2 = a3; j3 = a1; break;
        }
        int jb = (j1 << 8) | (j2 << 4) | j3;
        accv += mw[k] * out_y[(size_t)k * (DD * LL) + (jb >> 5) * LL + ((jb & 31) << 7) + dd];
    }
    out[idx] = accv;
}

extern "C" void kernel_launch(void* const* d_in, const int* in_sizes, int n_in,
                              void* d_out, int out_size, void* d_ws, size_t ws_size,
                              hipStream_t stream) {
    const float* x      = (const float*)d_in[0];
    const float* Wp     = (const float*)d_in[1];
    const float* Wdt    = (const float*)d_in[2];
    const float* bias   = (const float*)d_in[3];
    const float* A_logs = (const float*)d_in[4];
    const float* Ds     = (const float*)d_in[5];
    const float* mw     = (const float*)d_in[6];
    const float* mb     = (const float*)d_in[7];
    float* out = (float*)d_out;

    float* ws    = (float*)d_ws;
    float* delta = ws;                                  // K*L*D    = 6291456
    float* Bc    = delta + (size_t)KK * LL * DD;        // K*L*N    =  786432
    float* Cc    = Bc    + (size_t)KK * LL * NN;        // K*L*N    =  786432
    float* Sb    = Cc    + (size_t)KK * LL * NN;        // K*NC*D*N = 3145728
    float* dts   = Sb    + (size_t)KK * NC * DD * NN;   // K*NC*D   =  196608
    float* oy    = dts   + (size_t)KK * NC * DD;        // K*D*L    = 6291456

    proj_kernel <<<dim3(KK * (LL / 64)), dim3(256), 0, stream>>>(x, Wp, Wdt, bias, delta, Bc, Cc);
    scanA_kernel<<<dim3(KK * NC),        dim3(128), 0, stream>>>(x, delta, Bc, A_logs, Sb, dts);
    scanB_kernel<<<dim3(KK * DD * NN / 256), dim3(256), 0, stream>>>(Sb, dts, A_logs);
    scanC_kernel<<<dim3(KK * NC),        dim3(128), 0, stream>>>(x, delta, Bc, Cc, A_logs, Ds, Sb, oy);
    merge_kernel<<<dim3(LL * DD / 256),  dim3(256), 0, stream>>>(oy, mw, mb, out);
}

// Round 4
// 179.313 us; speedup vs baseline: 1.6548x; 1.0450x over previous
//
#include <hip/hip_runtime.h>

#define KK 12
#define LL 4096
#define DD 128
#define NN 16
#define RR 8
#define NC 64
#define LC 64
#define XST 132            // x-tile LDS stride (floats)
#define YST 66             // ybuf LDS stride (floats); 128*66 == 64*132
#define SDST 44            // x_dbl LDS row stride (floats)
#define XDBL_TILE (64 * SDST)   // 2816 floats per (k,chunk) tile

__device__ __forceinline__ int pos_of(int k, int l) {
    int o = k >> 1;
    int le = (k & 1) ? (4095 - l) : l;
    int t1 = le >> 8, t2 = (le >> 4) & 15, t3 = le & 15;
    switch (o) {
        case 0:  return (t1 << 8) | (t2 << 4) | t3;
        case 1:  return (t1 << 8) | (t3 << 4) | t2;
        case 2:  return (t3 << 8) | (t2 << 4) | t1;
        case 3:  return (t2 << 8) | (t3 << 4) | t1;
        case 4:  return (t2 << 8) | (t1 << 4) | t3;
        default: return (t3 << 8) | (t1 << 4) | t2;
    }
}

__device__ __forceinline__ float softplus_f(float z) {
    return fmaxf(z, 0.0f) + __logf(1.0f + __expf(-fabsf(z)));
}

// delta[l][d] recomputed from LDS x_dbl row (8 fma + softplus)
__device__ __forceinline__ float delta_at(const float* sdbl, int i,
                                          float4 w0, float4 w1, float bz) {
    const float4* dr = (const float4*)(sdbl + i * SDST);
    float4 r0 = dr[0], r1 = dr[1];
    float z = bz + w0.x * r0.x + w0.y * r0.y + w0.z * r0.z + w0.w * r0.w
                 + w1.x * r1.x + w1.y * r1.y + w1.z * r1.z + w1.w * r1.w;
    return softplus_f(z);
}

// e[j] = exp(tl * A[n0+j]); structured fast path uses q^(n+1), q = exp(tl*A0)
__device__ __forceinline__ void e8_vec(bool structured, int half, float tl,
                                       float A0, const float* A8, float* e) {
    if (structured) {
        float q = __expf(tl * A0);
        float q2 = q * q, q4 = q2 * q2, q8 = q4 * q4;
        e[0] = half ? q8 * q : q;          // q^(n0+1)
        #pragma unroll
        for (int j = 1; j < 8; j++) e[j] = e[j - 1] * q;
    } else {
        #pragma unroll
        for (int j = 0; j < 8; j++) e[j] = __expf(tl * A8[j]);
    }
}

__device__ __forceinline__ bool load_A8(const float* __restrict__ A_logs,
                                        int k, int d, int n0, float* A8, float& A0) {
    const float4* ap = (const float4*)(A_logs + ((size_t)(k * DD + d) * NN + n0));
    float4 a0 = ap[0], a1 = ap[1];
    A8[0] = -__expf(a0.x); A8[1] = -__expf(a0.y);
    A8[2] = -__expf(a0.z); A8[3] = -__expf(a0.w);
    A8[4] = -__expf(a1.x); A8[5] = -__expf(a1.y);
    A8[6] = -__expf(a1.z); A8[7] = -__expf(a1.w);
    A0 = -__expf(A_logs[(size_t)(k * DD + d) * NN]);
    bool s = true;
    #pragma unroll
    for (int j = 0; j < 8; j++) {
        float m = (float)(n0 + j + 1);
        s = s && (fabsf(A8[j] - m * A0) <= 1e-4f * m * fabsf(A0));
    }
    return s;
}

// ---------------------------------------------------------------------------
// K1: proj GEMM + phase A local scan. Block = (k, chunk), 256 threads.
// ---------------------------------------------------------------------------
__global__ __launch_bounds__(256) void k1_proj_scanA(
    const float* __restrict__ x, const float* __restrict__ Wp,
    const float* __restrict__ Wdt, const float* __restrict__ bias,
    const float* __restrict__ A_logs, const float* __restrict__ Ds,
    float* __restrict__ S, float* __restrict__ dtsum,
    float* __restrict__ oy, float* __restrict__ xdbl)
{
    const int blk = blockIdx.x;
    const int k = blk >> 6;
    const int c = blk & 63;
    const int l0 = c * LC;
    const int t = threadIdx.x;

    __shared__ float xs[64 * XST];    // x-tile; reused as ybuf[128][YST]
    __shared__ float sdbl[64 * SDST]; // x_dbl [l][c]: 0-7 dts, 8-23 B, 24-39 C
    __shared__ int   pos_s[64];

    if (t < 64) pos_s[t] = pos_of(k, l0 + t);
    __syncthreads();

    // ---- stage x tile (coalesced) ----
    {
        int lane32 = t & 31, rowi = t >> 5;
        #pragma unroll
        for (int p = 0; p < 8; p++) {
            int l = p * 8 + rowi;
            float4 v = *(const float4*)(x + (size_t)pos_s[l] * DD + lane32 * 4);
            *(float4*)(&xs[l * XST + lane32 * 4]) = v;
        }
    }
    __syncthreads();

    // ---- projection GEMM: wave cg computes 10 of 40 channels ----
    {
        int l = t & 63, cgch = t >> 6;
        float acc[10];
        #pragma unroll
        for (int j = 0; j < 10; j++) acc[j] = 0.0f;
        const float* wk = Wp + (size_t)(k * 40 + cgch * 10) * DD;
        for (int d4 = 0; d4 < DD; d4 += 4) {
            float4 xv = *(const float4*)(&xs[l * XST + d4]);
            #pragma unroll
            for (int j = 0; j < 10; j++) {
                const float* w = wk + j * DD + d4;   // wave-uniform
                acc[j] += xv.x * w[0] + xv.y * w[1] + xv.z * w[2] + xv.w * w[3];
            }
        }
        #pragma unroll
        for (int j = 0; j < 10; j++) sdbl[l * SDST + cgch * 10 + j] = acc[j];
    }
    __syncthreads();   // sdbl ready; xs free -> ybuf

    // ---- spill x_dbl tile for K3 (chunk 0 never needs correction) ----
    if (c != 0) {
        for (int idx = t; idx < XDBL_TILE; idx += 256)
            xdbl[(size_t)blk * XDBL_TILE + idx] = sdbl[idx];
    }

    // ---- scan setup: thread = (d, n-half) ----
    const int d = t >> 1, half = t & 1, n0 = half * 8;
    float A8[8], A0;
    bool structured = load_A8(A_logs, k, d, n0, A8, A0);
    const float4* wp4 = (const float4*)(Wdt + (size_t)(k * DD + d) * RR);
    const float4 w0 = wp4[0], w1 = wp4[1];
    const float bz = bias[k * DD + d];
    const float Dval = Ds[k * DD + d];
    float* ybuf = xs;   // [d][l] stride YST

    // ---- phase A: local scan (h0 = 0), y-local -> LDS ----
    {
        float h[8] = {0, 0, 0, 0, 0, 0, 0, 0};
        float dsum = 0.0f;
        #pragma unroll 4
        for (int i = 0; i < LC; i++) {
            float tl = delta_at(sdbl, i, w0, w1, bz);
            dsum += tl;
            float u = x[(size_t)pos_s[i] * DD + d];
            const float4* bp = (const float4*)(&sdbl[i * SDST + 8 + n0]);
            float4 b0 = bp[0], b1 = bp[1];
            const float4* cp = (const float4*)(&sdbl[i * SDST + 24 + n0]);
            float4 c0 = cp[0], c1 = cp[1];
            float e[8];
            e8_vec(structured, half, tl, A0, A8, e);
            float tu = tl * u;
            h[0] = e[0] * h[0] + tu * b0.x;  h[1] = e[1] * h[1] + tu * b0.y;
            h[2] = e[2] * h[2] + tu * b0.z;  h[3] = e[3] * h[3] + tu * b0.w;
            h[4] = e[4] * h[4] + tu * b1.x;  h[5] = e[5] * h[5] + tu * b1.y;
            h[6] = e[6] * h[6] + tu * b1.z;  h[7] = e[7] * h[7] + tu * b1.w;
            float yp = h[0] * c0.x + h[1] * c0.y + h[2] * c0.z + h[3] * c0.w
                     + h[4] * c1.x + h[5] * c1.y + h[6] * c1.z + h[7] * c1.w;
            float y = yp + __shfl_xor(yp, 1);
            if (!half) ybuf[d * YST + i] = y + Dval * u;
        }
        float4* sp = (float4*)(S + (((size_t)(k * NC + c) * DD + d) * NN + n0));
        sp[0] = make_float4(h[0], h[1], h[2], h[3]);
        sp[1] = make_float4(h[4], h[5], h[6], h[7]);
        if (!half) dtsum[(k * NC + c) * DD + d] = dsum;
    }
    __syncthreads();

    // ---- store y tile: oy[k][d][l] ----
    {
        int row = t >> 4, col = (t & 15) * 4;
        #pragma unroll
        for (int p = 0; p < 8; p++) {
            int r = p * 16 + row;
            float4 v = *(const float4*)(&ybuf[r * YST + col]);
            *(float4*)(oy + ((size_t)(k * DD + r)) * LL + l0 + col) = v;
        }
    }
}

// ---------------------------------------------------------------------------
// K2: sequential combine across chunks; S <- true initial state, in place.
// ---------------------------------------------------------------------------
__global__ __launch_bounds__(256) void k2_combine(
    float* __restrict__ S, const float* __restrict__ dtsum,
    const float* __restrict__ A_logs)
{
    int tid = blockIdx.x * 256 + threadIdx.x;   // k*2048 + d*16 + n
    int kk = tid >> 11, rem = tid & 2047, dd2 = rem >> 4;
    float Ac = -__expf(A_logs[tid]);
    float hh = 0.0f;
    #pragma unroll 8
    for (int c2 = 0; c2 < NC; c2++) {
        size_t base = ((size_t)(kk * NC + c2)) * 2048 + rem;
        float s = S[base];
        float dsv = dtsum[(kk * NC + c2) * DD + dd2];
        S[base] = hh;
        hh = s + __expf(dsv * Ac) * hh;
    }
}

// ---------------------------------------------------------------------------
// K3: correction pass. y(l) += C(l) . (prod_{j<=l} dA(j)) h0  (exact by
// linearity of the recurrence). Accumulate in LDS, then one coalesced RMW.
// ---------------------------------------------------------------------------
__global__ __launch_bounds__(256) void k3_corr(
    const float* __restrict__ Wdt, const float* __restrict__ bias,
    const float* __restrict__ A_logs, const float* __restrict__ S,
    const float* __restrict__ xdbl, float* __restrict__ oy)
{
    const int blk = blockIdx.x;
    const int k = blk >> 6;
    const int c = blk & 63;
    if (c == 0) return;                 // chunk 0 has h0 = 0
    const int l0 = c * LC;
    const int t = threadIdx.x;

    __shared__ float sdbl[64 * SDST];
    __shared__ float ybuf[128 * YST];

    for (int idx = t; idx < XDBL_TILE; idx += 256)
        sdbl[idx] = xdbl[(size_t)blk * XDBL_TILE + idx];
    for (int idx = t; idx < 128 * YST; idx += 256)
        ybuf[idx] = 0.0f;
    __syncthreads();

    const int d = t >> 1, half = t & 1, n0 = half * 8;
    float A8[8], A0;
    bool structured = load_A8(A_logs, k, d, n0, A8, A0);
    const float4* wp4 = (const float4*)(Wdt + (size_t)(k * DD + d) * RR);
    const float4 w0 = wp4[0], w1 = wp4[1];
    const float bz = bias[k * DD + d];

    float corr[8];
    {
        const float4* hp = (const float4*)(S + (((size_t)(k * NC + c) * DD + d) * NN + n0));
        float4 h40 = hp[0], h41 = hp[1];
        corr[0] = h40.x; corr[1] = h40.y; corr[2] = h40.z; corr[3] = h40.w;
        corr[4] = h41.x; corr[5] = h41.y; corr[6] = h41.z; corr[7] = h41.w;
    }

    bool alive = true;
    for (int ii = 0; ii < 8 && alive; ii++) {
        #pragma unroll
        for (int jj = 0; jj < 8; jj++) {
            int i = ii * 8 + jj;
            float tl = delta_at(sdbl, i, w0, w1, bz);
            float e[8];
            e8_vec(structured, half, tl, A0, A8, e);
            #pragma unroll
            for (int j = 0; j < 8; j++) corr[j] *= e[j];
            const float4* cp = (const float4*)(&sdbl[i * SDST + 24 + n0]);
            float4 c0 = cp[0], c1 = cp[1];
            float yp = corr[0] * c0.x + corr[1] * c0.y + corr[2] * c0.z + corr[3] * c0.w
                     + corr[4] * c1.x + corr[5] * c1.y + corr[6] * c1.z + corr[7] * c1.w;
            float y = yp + __shfl_xor(yp, 1);
            if (!half) ybuf[d * YST + i] = y;
        }
        float mag = fabsf(corr[0]) + fabsf(corr[1]) + fabsf(corr[2]) + fabsf(corr[3])
                  + fabsf(corr[4]) + fabsf(corr[5]) + fabsf(corr[6]) + fabsf(corr[7]);
        if (__all(mag == 0.0f)) alive = false;   // remaining ybuf stays 0
    }
    __syncthreads();

    // ---- RMW oy tile ----
    {
        int row = t >> 4, col = (t & 15) * 4;
        #pragma unroll
        for (int p = 0; p < 8; p++) {
            int r = p * 16 + row;
            float4* addr = (float4*)(oy + ((size_t)(k * DD + r)) * LL + l0 + col);
            float4 v = *addr;
            const float4 w = *(const float4*)(&ybuf[r * YST + col]);
            v.x += w.x; v.y += w.y; v.z += w.z; v.w += w.w;
            *addr = v;
        }
    }
}

// ---------------------------------------------------------------------------
// K4: restore + merge (reference's (D,L)-flat reshape semantics).
// ---------------------------------------------------------------------------
__global__ __launch_bounds__(256) void k4_merge(
    const float* __restrict__ out_y, const float* __restrict__ mw,
    const float* __restrict__ mb, float* __restrict__ out)
{
    int idx = blockIdx.x * 256 + threadIdx.x;
    int dd = idx & 127;
    int p = idx >> 7;
    int i3 = p & 15, i2 = (p >> 4) & 15, i1 = (p >> 8) & 15;

    float accv = mb[0];
    #pragma unroll
    for (int k = 0; k < 12; k++) {
        int a1 = i1, a2 = i2, a3 = i3;
        if (k & 1) { a1 = 15 - i1; a2 = 15 - i2; a3 = 15 - i3; }
        int j1, j2, j3;
        switch (k >> 1) {
            case 0:  j1 = a1; j2 = a2; j3 = a3; break;
            case 1:  j1 = a1; j2 = a3; j3 = a2; break;
            case 2:  j1 = a3; j2 = a2; j3 = a1; break;
            case 3:  j1 = a3; j2 = a1; j3 = a2; break;
            case 4:  j1 = a2; j2 = a1; j3 = a3; break;
            default: j1 = a2; j2 = a3; j3 = a1; break;
        }
        int jb = (j1 << 8) | (j2 << 4) | j3;
        accv += mw[k] * out_y[(size_t)k * (DD * LL) + (jb >> 5) * LL
                              + ((jb & 31) << 7) + dd];
    }
    out[idx] = accv;
}

extern "C" void kernel_launch(void* const* d_in, const int* in_sizes, int n_in,
                              void* d_out, int out_size, void* d_ws, size_t ws_size,
                              hipStream_t stream) {
    const float* x      = (const float*)d_in[0];
    const float* Wp     = (const float*)d_in[1];
    const float* Wdt    = (const float*)d_in[2];
    const float* bias   = (const float*)d_in[3];
    const float* A_logs = (const float*)d_in[4];
    const float* Ds     = (const float*)d_in[5];
    const float* mw     = (const float*)d_in[6];
    const float* mb     = (const float*)d_in[7];
    float* out = (float*)d_out;

    float* ws   = (float*)d_ws;
    float* S    = ws;                                 // K*NC*D*N = 1572864
    float* dts  = S + (size_t)KK * NC * DD * NN;      // K*NC*D   =   98304
    float* oy   = dts + (size_t)KK * NC * DD;         // K*D*L    = 6291456
    float* xdbl = oy + (size_t)KK * DD * LL;          // 768*2816 = 2162688

    k1_proj_scanA<<<dim3(KK * NC), dim3(256), 0, stream>>>(
        x, Wp, Wdt, bias, A_logs, Ds, S, dts, oy, xdbl);
    k2_combine<<<dim3(KK * DD * NN / 256), dim3(256), 0, stream>>>(S, dts, A_logs);
    k3_corr<<<dim3(KK * NC), dim3(256), 0, stream>>>(Wdt, bias, A_logs, S, xdbl, oy);
    k4_merge<<<dim3(LL * DD / 256), dim3(256), 0, stream>>>(oy, mw, mb, out);
}